// Round 11
// baseline (267.974 us; speedup 1.0000x reference)
//
#include <hip/hip_runtime.h>
#include <hip/hip_bf16.h>

// NLM_7962869366897: fused per-feature GLU-MLP, two-phase.
// Phase A: transpose w1a -> wsA [2048][128][32] bf16; w1b -> wsB [2048][128] f32.
// Phase B: per-d GEMM [512x32]@[32x128] via mfma_f32_16x16x32_bf16 (K=32),
//          depth-2 state pipeline (4KB in flight/wave), weights direct from wsA.

#define NB 512
#define ND 2048
#define NM 32
#define NH2 128  // 2H

typedef __bf16 bf16x8 __attribute__((ext_vector_type(8)));
typedef float f32x4 __attribute__((ext_vector_type(4)));
typedef float f32x2 __attribute__((ext_vector_type(2)));

#define WSA_BYTES ((size_t)ND * NH2 * NM * 2)   // 16.8 MB bf16

__device__ __forceinline__ float sigmoid_fast(float x) {
    return __builtin_amdgcn_rcpf(1.0f + __builtin_amdgcn_exp2f(-1.442695040888963f * x));
}

// ---------------- Phase A: weight transpose (unchanged from r10) ----------------
__global__ __launch_bounds__(256) void transpose_w(const float* __restrict__ w1a,
                                                   const float* __restrict__ w1b,
                                                   __bf16* __restrict__ wsA,
                                                   float* __restrict__ wsB) {
    __shared__ float tile[64 * 65];
    const int tid = threadIdx.x;
    if (blockIdx.x < 2048) {
        const int h0 = (blockIdx.x & 63) * 2;
        const int d0 = (blockIdx.x >> 6) * 64;
        const int dc = tid & 63, wv = tid >> 6;
        #pragma unroll
        for (int k = 0; k < 16; ++k) {
            const int rr = wv + 4 * k;
            const int m = rr >> 1, hh = rr & 1;
            tile[rr * 65 + dc] = w1a[(size_t)(m * 128 + h0 + hh) * ND + d0 + dc];
        }
        __syncthreads();
        const int dloc = tid >> 2, seg = tid & 3;
        bf16x8 u0, u1;
        #pragma unroll
        for (int i = 0; i < 8; ++i) {
            const int q0 = seg * 16 + i;        // q' = hh*32 + m
            u0[i] = (__bf16)tile[((q0 & 31) * 2 + (q0 >> 5)) * 65 + dloc];
            const int q1 = seg * 16 + 8 + i;
            u1[i] = (__bf16)tile[((q1 & 31) * 2 + (q1 >> 5)) * 65 + dloc];
        }
        __bf16* dst = wsA + (size_t)(d0 + dloc) * (NH2 * NM) + h0 * 32 + seg * 16;
        *(bf16x8*)dst = u0;
        *(bf16x8*)(dst + 8) = u1;
    } else {
        const int d0 = (blockIdx.x - 2048) * 16;
        const int dcol = tid & 15, pr = tid >> 4;
        #pragma unroll
        for (int k = 0; k < 8; ++k) {
            const int p = pr + 16 * k;
            tile[p * 17 + dcol] = w1b[(size_t)p * ND + d0 + dcol];
        }
        __syncthreads();
        const int dloc = tid >> 4, j = tid & 15;
        #pragma unroll
        for (int i = 0; i < 8; ++i) {
            const int row = j * 8 + i;
            wsB[(size_t)(d0 + dloc) * 128 + j * 8 + i] = tile[row * 17 + dloc];
        }
    }
}

// ---------------- Phase B: fused compute, depth-2 state pipeline ----------------
__global__ __launch_bounds__(256, 4) void nlm_fused(
    const float*  __restrict__ st,   // [B, D, M]
    const __bf16* __restrict__ wsA,  // [D][128][32] bf16
    const float*  __restrict__ b1a,  // [1, D, 2H]
    const float*  __restrict__ Ta,
    const float*  __restrict__ wsB,  // [D][128] f32 (h*2+c)
    const float*  __restrict__ b1b,  // [1, D, 2]
    const float*  __restrict__ Tb,
    float*        __restrict__ out)  // [B, D]
{
    const int d    = blockIdx.x;
    const int tid  = threadIdx.x;
    const int wave = tid >> 6;
    const int lane = tid & 63;
    const int l15  = lane & 15;
    const int lg   = lane >> 4;     // 0..3

    // ---- state loads FIRST (critical path): tiles 0 and 1 of this wave's 8 ----
    const int bbase = wave * 128;
    const size_t TSTR = (size_t)16 * ND * NM;   // elements between b-tiles
    const float* sp = st + ((size_t)(bbase + l15) * ND + d) * NM + lg * 8;
    f32x4 sA0 = *(const f32x4*)sp;
    f32x4 sA1 = *(const f32x4*)(sp + 4);
    f32x4 sB0 = *(const f32x4*)(sp + TSTR);
    f32x4 sB1 = *(const f32x4*)(sp + TSTR + 4);

    // ---- weights/bias after (L2/L3-resident, reused all 8 tiles) ----
    const __bf16* wA = wsA + (size_t)d * (NH2 * NM);
    bf16x8 afrag[8];
    #pragma unroll
    for (int t = 0; t < 8; ++t)
        afrag[t] = *(const bf16x8*)(wA + (t * 16 + l15) * 32 + lg * 8);

    f32x4 bias[8];
    #pragma unroll
    for (int t = 0; t < 8; ++t)
        bias[t] = *(const f32x4*)(b1a + (size_t)d * 128 + t * 16 + lg * 4);

    const float* w2d = wsB + (size_t)d * 128;
    float w2a[4][4], w2b[4][4];
    #pragma unroll
    for (int t = 0; t < 4; ++t)
        #pragma unroll
        for (int r = 0; r < 4; ++r) {
            const int h = t * 16 + lg * 4 + r;
            f32x2 p = *(const f32x2*)(w2d + h * 2);
            w2a[t][r] = p[0];
            w2b[t][r] = p[1];
        }

    const float rTa = 1.0f / Ta[0];
    const float rTb = 1.0f / Tb[0];
    const float bb0 = b1b[d * 2 + 0];
    const float bb1 = b1b[d * 2 + 1];

    // ---- main loop: 8 tiles of 16 batches; depth-2 pipeline, fully unrolled ----
    #pragma unroll
    for (int bt = 0; bt < 8; ++bt) {
        f32x4 c0, c1;
        if ((bt & 1) == 0) {
            c0 = sA0; c1 = sA1;
            if (bt < 6) {   // prefetch tile bt+2 into slot A
                const float* p = sp + (size_t)(bt + 2) * TSTR;
                sA0 = *(const f32x4*)p;
                sA1 = *(const f32x4*)(p + 4);
            }
        } else {
            c0 = sB0; c1 = sB1;
            if (bt < 6) {   // prefetch tile bt+2 into slot B
                const float* p = sp + (size_t)(bt + 2) * TSTR;
                sB0 = *(const f32x4*)p;
                sB1 = *(const f32x4*)(p + 4);
            }
        }

        bf16x8 bfrag;
        #pragma unroll
        for (int j = 0; j < 4; ++j) {
            bfrag[j]     = (__bf16)c0[j];
            bfrag[j + 4] = (__bf16)c1[j];
        }
        f32x4 acc[8];
        #pragma unroll
        for (int t = 0; t < 8; ++t) acc[t] = bias[t];
        #pragma unroll
        for (int t = 0; t < 8; ++t)
            acc[t] = __builtin_amdgcn_mfma_f32_16x16x32_bf16(afrag[t], bfrag, acc[t], 0, 0, 0);

        // GLU pairs (h, h+64) = tiles (t, t+4), same reg r; lane holds batch l15.
        float z0 = 0.0f, z1 = 0.0f;
        #pragma unroll
        for (int t = 0; t < 4; ++t)
            #pragma unroll
            for (int r = 0; r < 4; ++r) {
                const float ya = acc[t][r]     * rTa;
                const float yb = acc[t + 4][r] * rTa;
                const float g  = ya * sigmoid_fast(yb);
                z0 = fmaf(g, w2a[t][r], z0);
                z1 = fmaf(g, w2b[t][r], z1);
            }
        z0 += __shfl_xor(z0, 16);
        z0 += __shfl_xor(z0, 32);
        z1 += __shfl_xor(z1, 16);
        z1 += __shfl_xor(z1, 32);
        if (lg == 0) {
            const float za = (z0 + bb0) * rTb;
            const float zb = (z1 + bb1) * rTb;
            out[(size_t)(bbase + bt * 16 + l15) * ND + d] = za * sigmoid_fast(zb);
        }
    }
}

extern "C" void kernel_launch(void* const* d_in, const int* in_sizes, int n_in,
                              void* d_out, int out_size, void* d_ws, size_t ws_size,
                              hipStream_t stream) {
    const float* st  = (const float*)d_in[0];
    const float* w1a = (const float*)d_in[1];
    const float* b1a = (const float*)d_in[2];
    const float* Ta  = (const float*)d_in[3];
    const float* w1b = (const float*)d_in[4];
    const float* b1b = (const float*)d_in[5];
    const float* Tb  = (const float*)d_in[6];
    float* out = (float*)d_out;

    __bf16* wsA = (__bf16*)d_ws;
    float*  wsB = (float*)((char*)d_ws + WSA_BYTES);

    transpose_w<<<dim3(2048 + 128), dim3(256), 0, stream>>>(w1a, w1b, wsA, wsB);
    nlm_fused<<<dim3(ND), dim3(256), 0, stream>>>(st, wsA, b1a, Ta, wsB, b1b, Tb, out);
}